// Round 14
// baseline (437.813 us; speedup 1.0000x reference)
//
#include <hip/hip_runtime.h>
#include <hip/hip_fp16.h>

#define NROW 32768
#define DIM  256
#define NC   8192
#define CAP  16384                     // max rescued rows (expect ~2500)
#define MARGINF 0.25f                  // flag threshold: not-flagged => true cheap gap >= 0.125
#define BIAS 512.0f                    // cheap-score bias: guarantees all cheap scores negative
#define AST 576                        // A' row: [hi 256 | ones 32 | lo 256 | pad 32] halves
#define BST 576                        // B' row: [hi 256 | ch 32   | lo 256 | pad 32] halves
#define LOSS_SCALE (1.0f / 8388608.0f)

typedef __attribute__((ext_vector_type(8))) _Float16 half8;
typedef __attribute__((ext_vector_type(4))) _Float16 half4;
typedef __attribute__((ext_vector_type(4))) float   floatx4;
typedef const __attribute__((address_space(1))) void* gas_p;
typedef __attribute__((address_space(3))) void*       las_p;

static __device__ __forceinline__ unsigned short f2hb(float f) {
    _Float16 h = (_Float16)f;
    unsigned short u;
    __builtin_memcpy(&u, &h, 2);
    return u;
}
static __device__ __forceinline__ unsigned umin_(unsigned a, unsigned b) { return a < b ? a : b; }
static __device__ __forceinline__ unsigned umax_(unsigned a, unsigned b) { return a > b ? a : b; }

// ======================= prep kernels (fast path) =======================

__global__ void prep_a_k(const float* __restrict__ x, unsigned short* __restrict__ Ah,
                         float* __restrict__ norms) {
    int row  = blockIdx.x * 4 + (threadIdx.x >> 6);
    int lane = threadIdx.x & 63;
    const float4 v = ((const float4*)(x + (size_t)row * DIM))[lane];
    float s = v.x * v.x + v.y * v.y + v.z * v.z + v.w * v.w;
#pragma unroll
    for (int off = 32; off; off >>= 1) s += __shfl_down(s, off, 64);
    if (lane == 0) norms[row] = s;
    ushort4 hi4 = make_ushort4(f2hb(v.x), f2hb(v.y), f2hb(v.z), f2hb(v.w));
    ushort4 lo4 = make_ushort4(f2hb(v.x - (float)(_Float16)v.x),
                               f2hb(v.y - (float)(_Float16)v.y),
                               f2hb(v.z - (float)(_Float16)v.z),
                               f2hb(v.w - (float)(_Float16)v.w));
    unsigned short* rp = Ah + (size_t)row * AST;
    *(ushort4*)(rp + lane * 4)       = hi4;
    *(ushort4*)(rp + 288 + lane * 4) = lo4;
    if (lane < 8) {                    // legacy ones block (unused by cheap)
        ushort4 ob = make_ushort4(0, 0, 0, 0);
        if (lane == 0) { ob.x = 0x3C00; ob.y = 0x3C00; }
        *(ushort4*)(rp + 256 + lane * 4) = ob;
    }
}

__global__ void code_norms_k(const float* __restrict__ e, unsigned short* __restrict__ Bh,
                             float* __restrict__ cHalf) {
    int j = blockIdx.x * 256 + threadIdx.x;
    float s = 0.f;
    for (int d = 0; d < DIM; ++d) { float v = e[(size_t)d * NC + j]; s += v * v; }
    cHalf[j] = 0.5f * s;
    float t = -0.5f * s - BIAS;        // legacy ch block (unused by cheap)
    unsigned short hi = f2hb(t);
    _Float16 hf; __builtin_memcpy(&hf, &hi, 2);
    unsigned short lo = f2hb(t - (float)hf);
    unsigned short* p = Bh + (size_t)j * BST + 256;
    p[0] = hi; p[1] = lo;
    for (int k2 = 2; k2 < 32; ++k2) p[k2] = 0;
}

__global__ void prep_b_k(const float* __restrict__ e, unsigned short* __restrict__ Bh) {
    __shared__ float t[32][33];
    int jb = blockIdx.x * 32, db = blockIdx.y * 32;
#pragma unroll
    for (int i = 0; i < 4; ++i)
        t[threadIdx.y + i * 8][threadIdx.x] =
            e[(size_t)(db + threadIdx.y + i * 8) * NC + jb + threadIdx.x];
    __syncthreads();
#pragma unroll
    for (int i = 0; i < 4; ++i) {
        int j = jb + threadIdx.y + i * 8;
        int d = db + threadIdx.x;
        float val = t[threadIdx.x][threadIdx.y + i * 8];
        Bh[(size_t)j * BST + d]       = f2hb(val);
        Bh[(size_t)j * BST + 288 + d] = f2hb(val - (float)(_Float16)val);
    }
}

// ======================= R21 cheap kernel: B direct-from-global (LDS B eliminated) =======================
// R20 post-mortem: occupancy doubled (42.6%) but perf regressed -> latency/occupancy was
// never binding; LDS THROUGHPUT is. Every scheduling variant failed because ~900 cyc/body
// of LDS service (A reads + B reads + B stage writes + conflicts) shares one pipe with
// the MFMA operand feed.
// R21 removes B from LDS entirely: the mfma B-fragment is per-lane Bh[(col)*BST + c*32
// + lq*8], 16 B -> a direct global dwordx4 with 4 lanes/col = 16 fully-used 64B lines
// per instr, L2-resident (B = 9.4 MB), async into REGISTERS (no LDS write/read, no
// barrier; compiler inserts the precise vmcnt before the consuming MFMA).
//   - LDS/body: A frag reads only (4 ds_read_b128/wave ~ 375 cyc/CU + ~130 conflicts)
//     vs R15's ~900. B's ~585 cyc moves to the concurrent vmem/L2 pipe; the wr-partner
//     wave rereads the same 16 KB -> likely L1 hits.
//   - Main loop: ZERO barriers, ZERO LDS writes (A+chl read-only after one prologue
//     barrier). All hazards wave-local. Tail prefetch wraps to chunk 0 (never consumed).
//   - Double-buffered af2/bf2 by body parity (c&1; 8 bodies/jt keeps parity static),
//     prefetch issued BEFORE the MFMA cluster (sched_barrier pins the order) -> one full
//     body (~700+ cyc) of latency cover for the L2 loads (~200-400 cyc).
//   - Registers: af2 32 + bf2 32 + k1/k2 32 + B ptrs 8 + misc ~12 = ~116 arch + 64 AGPR
//     = ~180 <= 188 (R15's proven no-spill level). A stays fully in LDS (no ar[]).
// Geometry unchanged from R15: block 128 rows x 2048 cols (js 4-way), grid 1024, 8 waves,
// wave tile 64x64. A swizzle unchanged: LDS granule g of row r holds global k-granule
// (g&3)^s(r), s(r)=(r&3)^((r>>2)&3).

__global__ __launch_bounds__(512, 2) void vq_cheap_k(
    const unsigned short* __restrict__ Ah, const unsigned short* __restrict__ Bh,
    const float* __restrict__ cHalf,
    float* __restrict__ pv, int* __restrict__ pj, float* __restrict__ psv)
{
    __shared__ __align__(16) _Float16 Asl[8][4096];   // 64 KB: A-hi resident (read-only after prologue)
    __shared__ float chl[2048];                       //  8 KB

    const int tid  = threadIdx.x;
    const int js   = blockIdx.x & 3;
    const int rb   = blockIdx.x >> 2;
    const int row0 = rb * 128, col0 = js * 2048;
    const int lane = tid & 63, l15 = lane & 15, lq = lane >> 4;
    const int wave = tid >> 6;                 // 0..7
    const int wr = (wave >> 2) * 64;           // 0 / 64
    const int wc = (wave & 3) * 64;            // 0 / 64 / 128 / 192
    const int sr = tid >> 2;                   // A staging row 0..127
    const int ks = (((tid & 3) ^ (sr & 3) ^ ((sr >> 2) & 3))) * 8;  // A swizzled k-offset

    // ---- chl: cHalf + BIAS -> LDS ----
    {
        float4 a = ((const float4*)(cHalf + col0))[tid];
        a.x += BIAS; a.y += BIAS; a.z += BIAS; a.w += BIAS;
        ((float4*)chl)[tid] = a;
    }

    // ---- A-hi -> LDS (one inst per chunk) ----
    const unsigned short* Abase = Ah + (size_t)(row0 + sr) * AST + ks;
#pragma unroll
    for (int c = 0; c < 8; ++c)
        __builtin_amdgcn_global_load_lds((gas_p)(Abase + c * 32), (las_p)&Asl[c][tid * 8], 16, 0, 0);

    // ---- per-lane B fragment base pointers (cf = 0..3) ----
    // frag(jt, c)[cf] = 16B at Bb[cf] + jt*(256*BST) + c*32   (halves)
    const unsigned short* Bb0 = Bh + (size_t)(col0 + wc +  0 + l15) * BST + lq * 8;
    const unsigned short* Bb1 = Bh + (size_t)(col0 + wc + 16 + l15) * BST + lq * 8;
    const unsigned short* Bb2 = Bh + (size_t)(col0 + wc + 32 + l15) * BST + lq * 8;
    const unsigned short* Bb3 = Bh + (size_t)(col0 + wc + 48 + l15) * BST + lq * 8;

    unsigned k1[16], k2[16];
#pragma unroll
    for (int s = 0; s < 16; ++s) { k1[s] = 0xFFFFFFFFu; k2[s] = 0xFFFFFFFFu; }

    const floatx4 fzero = {0.0f, 0.0f, 0.0f, 0.0f};
    floatx4 acc[4][4];
#pragma unroll
    for (int rf = 0; rf < 4; ++rf)
#pragma unroll
        for (int cf = 0; cf < 4; ++cf) acc[rf][cf] = fzero;

    // prologue drain (once): A staged + chl written, publish to all waves
    asm volatile("s_waitcnt vmcnt(0) lgkmcnt(0)" ::: "memory");
    __builtin_amdgcn_s_barrier();

    // ---- prime parity slot 0 with chunk 0 (jt=0,c=0) ----
    half8 af2[2][4], bf2[2][4];
    bf2[0][0] = *(const half8*)(Bb0);
    bf2[0][1] = *(const half8*)(Bb1);
    bf2[0][2] = *(const half8*)(Bb2);
    bf2[0][3] = *(const half8*)(Bb3);
#pragma unroll
    for (int rf = 0; rf < 4; ++rf) {
        const int m = wr + rf * 16 + l15;
        const int g = lq ^ (m & 3) ^ ((m >> 2) & 3);
        af2[0][rf] = *(const half8*)&Asl[0][m * 32 + g * 8];
    }

    for (int jt = 0; jt < 8; ++jt) {
#pragma unroll
        for (int c = 0; c < 8; ++c) {
            const int cur = c & 1;              // body T = jt*8+c; parity T&1 = c&1
            const int nxt = cur ^ 1;
            const int cn  = (c + 1) & 7;
            const int jtn = (c == 7) ? ((jt + 1) & 7) : jt;   // tail wraps -> dummy prefetch

            // prefetch next body's operands: B from global (async, registers),
            // A frags from resident LDS. Issued BEFORE the MFMAs for latency cover.
            {
                const size_t boff = (size_t)jtn * (256 * BST) + (size_t)cn * 32;
                bf2[nxt][0] = *(const half8*)(Bb0 + boff);
                bf2[nxt][1] = *(const half8*)(Bb1 + boff);
                bf2[nxt][2] = *(const half8*)(Bb2 + boff);
                bf2[nxt][3] = *(const half8*)(Bb3 + boff);
            }
#pragma unroll
            for (int rf = 0; rf < 4; ++rf) {
                const int m = wr + rf * 16 + l15;
                const int g = lq ^ (m & 3) ^ ((m >> 2) & 3);
                af2[nxt][rf] = *(const half8*)&Asl[cn][m * 32 + g * 8];
            }
            __builtin_amdgcn_sched_barrier(0);  // keep prefetch above the MFMAs

            // MFMA chunk T: operands loaded last body (compiler inserts exact
            // vmcnt/lgkm waits for the cur-slot loads)
            __builtin_amdgcn_s_setprio(1);
#pragma unroll
            for (int rf = 0; rf < 4; ++rf)
#pragma unroll
                for (int cf = 0; cf < 4; ++cf)
                    acc[rf][cf] = __builtin_amdgcn_mfma_f32_16x16x32_f16(
                        af2[cur][rf], bf2[cur][cf], acc[rf][cf], 0, 0, 0);
            __builtin_amdgcn_s_setprio(0);

            if (c == 7) {
                // ---- per-jt epilogue (chl is LDS read-only; no barriers anywhere) ----
#pragma unroll
                for (int cf = 0; cf < 4; ++cf) {
                    const unsigned colb = (unsigned)(jt * 256 + wc + cf * 16 + l15); // 11-bit local col
                    const float chv = chl[colb];
#pragma unroll
                    for (int rf = 0; rf < 4; ++rf)
#pragma unroll
                        for (int r = 0; r < 4; ++r) {
                            float s = acc[rf][cf][r] - chv;
                            unsigned key = (__float_as_uint(s) & 0xFFFFF800u) | colb;
                            int slot = rf * 4 + r;
                            unsigned t = umax_(key, k1[slot]);
                            k1[slot] = umin_(k1[slot], key);
                            k2[slot] = umin_(k2[slot], t);
                        }
                }
#pragma unroll
                for (int rf = 0; rf < 4; ++rf)
#pragma unroll
                    for (int cf = 0; cf < 4; ++cf) acc[rf][cf] = fzero;
            }
        }
    }

    // ---- cross-lane merge over the 16 l15-lanes of each row-group ----
#pragma unroll
    for (int st = 1; st < 16; st <<= 1) {
#pragma unroll
        for (int s = 0; s < 16; ++s) {
            unsigned o1 = (unsigned)__shfl_xor((int)k1[s], st, 64);
            unsigned o2 = (unsigned)__shfl_xor((int)k2[s], st, 64);
            unsigned t = umax_(k1[s], o1);
            k1[s] = umin_(k1[s], o1);
            k2[s] = umin_(umin_(k2[s], o2), t);
        }
    }

    // ---- merge the four column-group waves per row through LDS ----
    __syncthreads();                            // everything else drained (registers only)
    unsigned* mk1 = (unsigned*)&Asl[0][0];      // [128 rows][4 col-groups]
    unsigned* mk2 = (unsigned*)&Asl[1][0];
    if (l15 == 0) {
#pragma unroll
        for (int rf = 0; rf < 4; ++rf)
#pragma unroll
            for (int r = 0; r < 4; ++r) {
                int rloc = wr + rf * 16 + lq * 4 + r;
                int slot = rf * 4 + r;
                mk1[rloc * 4 + (wave & 3)] = k1[slot];
                mk2[rloc * 4 + (wave & 3)] = k2[slot];
            }
    }
    __syncthreads();
    if (tid < 128) {
        unsigned a0 = mk1[tid * 4], a1 = mk1[tid * 4 + 1], a2 = mk1[tid * 4 + 2], a3 = mk1[tid * 4 + 3];
        unsigned x = umin_(a0, a1), y = umax_(a0, a1);
        unsigned z = umin_(a2, a3), w = umax_(a2, a3);
        unsigned m1  = umin_(x, z);
        unsigned sm1 = umin_(umax_(x, z), umin_(y, w));            // 2nd-best of the four bests
        unsigned s0 = mk2[tid * 4], s1 = mk2[tid * 4 + 1], s2 = mk2[tid * 4 + 2], s3 = mk2[tid * 4 + 3];
        unsigned m2 = umin_(umin_(umin_(s0, s1), umin_(s2, s3)), sm1);
        pv[(size_t)js * NROW + row0 + tid]  = __uint_as_float(m1 & 0xFFFFF800u);
        pj[(size_t)js * NROW + row0 + tid]  = (int)(m1 & 2047u) + js * 2048;
        psv[(size_t)js * NROW + row0 + tid] = __uint_as_float(m2 & 0xFFFFF800u);
    }
}

// ======================= rescue GEMM: R19 — 3-deep ring + counted vmcnt =======================

template<bool RESCUE>
static __device__ __forceinline__ void chunk_off(int c, int& ac, int& bc) {
    if constexpr (RESCUE) {
        if (c < 8)       { ac = c * 32;              bc = c * 32; }
        else if (c < 16) { ac = (c - 8) * 32;        bc = 288 + (c - 8) * 32; }
        else             { ac = 288 + (c - 16) * 32; bc = (c - 16) * 32; }
    } else {
        ac = c * 32; bc = c * 32;
    }
}

#define GWAIT asm volatile("s_waitcnt vmcnt(4) lgkmcnt(0)\n\ts_barrier" ::: "memory")

template<int CHUNKS, int JT, int JSB, bool RESCUE>
__global__ __launch_bounds__(256, 2) void vq_gemm_k(
    const unsigned short* __restrict__ Ah, const unsigned short* __restrict__ Bh,
    const float* __restrict__ cHalf,
    float* __restrict__ pv, int* __restrict__ pj, float* __restrict__ psv,
    const int* __restrict__ list, const int* __restrict__ cnt)
{
    static_assert(CHUNKS % 3 == 0, "3-deep ring requires CHUNKS % 3 == 0");
    __shared__ __align__(16) _Float16 As[3][4096];    // 24 KB
    __shared__ __align__(16) _Float16 Bs[3][4096];    // 24 KB

    const int tid  = threadIdx.x;
    const int js   = blockIdx.x & ((1 << JSB) - 1);
    const int rb   = blockIdx.x >> JSB;
    const int row0 = rb * 128, col0 = js * (JT * 128);
    const int lane = tid & 63, l15 = lane & 15, lq = lane >> 4;
    const int wave = tid >> 6;
    const int wrow = (wave >> 1) * 64, wcol = (wave & 1) * 64;
    const int sr = tid >> 2, sp = (tid & 3) * 8;

    int nact = 0;
    if constexpr (RESCUE) {
        nact = *cnt;
        if (row0 >= nact) return;
    }

    const unsigned short *Abase0, *Abase1;
    if constexpr (RESCUE) {
        int i0 = row0 + sr, i1 = i0 + 64;
        int r0 = (i0 < nact) ? list[i0] : 0;
        int r1 = (i1 < nact) ? list[i1] : 0;
        Abase0 = Ah + (size_t)r0 * AST + sp;
        Abase1 = Ah + (size_t)r1 * AST + sp;
    } else {
        Abase0 = Ah + (size_t)(row0 + sr) * AST + sp;
        Abase1 = Abase0 + 64 * AST;
    }

    unsigned k1[16], k2[16];
    float bvf[16]; int bjf[16];
#pragma unroll
    for (int s = 0; s < 16; ++s) {
        k1[s] = 0xFFFFFFFFu; k2[s] = 0xFFFFFFFFu;
        bvf[s] = -3.4e38f; bjf[s] = 0;
    }

    const floatx4 fzero = {0.0f, 0.0f, 0.0f, 0.0f};
    floatx4 acc[4][4];
#pragma unroll
    for (int rf = 0; rf < 4; ++rf)
#pragma unroll
        for (int cf = 0; cf < 4; ++cf) acc[rf][cf] = fzero;

    const unsigned short* Bb0 = Bh + (size_t)(col0 + sr) * BST + sp;

#define LOAD4T(JT_, C_)                                                                      \
    do {                                                                                     \
        int an_, bn_;                                                                        \
        chunk_off<RESCUE>((C_), an_, bn_);                                                   \
        const unsigned short* bb_ = Bb0 + (size_t)(JT_) * (128 * BST);                       \
        _Float16* la_ = &As[(C_) % 3][tid * 8];                                              \
        _Float16* lb_ = &Bs[(C_) % 3][tid * 8];                                              \
        __builtin_amdgcn_global_load_lds((gas_p)(Abase0 + an_),            (las_p)la_,          16, 0, 0); \
        __builtin_amdgcn_global_load_lds((gas_p)(Abase1 + an_),            (las_p)(la_ + 2048), 16, 0, 0); \
        __builtin_amdgcn_global_load_lds((gas_p)(bb_ + bn_),               (las_p)lb_,          16, 0, 0); \
        __builtin_amdgcn_global_load_lds((gas_p)(bb_ + 64 * BST + bn_),    (las_p)(lb_ + 2048), 16, 0, 0); \
    } while (0)

    LOAD4T(0, 0);
    LOAD4T(0, 1);

    for (int jt = 0; jt < JT; ++jt) {
#pragma unroll
        for (int c = 0; c < CHUNKS; ++c) {
            GWAIT;
            if (c + 2 < CHUNKS)       LOAD4T(jt, c + 2);
            else if (jt + 1 < JT)     LOAD4T(jt + 1, c + 2 - CHUNKS);

            half8 af[4], bf[4];
#pragma unroll
            for (int rf = 0; rf < 4; ++rf)
                af[rf] = *(const half8*)&As[c % 3][(wrow + rf * 16 + l15) * 32 + lq * 8];
#pragma unroll
            for (int cf = 0; cf < 4; ++cf)
                bf[cf] = *(const half8*)&Bs[c % 3][(wcol + cf * 16 + l15) * 32 + lq * 8];
#pragma unroll
            for (int rf = 0; rf < 4; ++rf)
#pragma unroll
                for (int cf = 0; cf < 4; ++cf)
                    acc[rf][cf] = __builtin_amdgcn_mfma_f32_16x16x32_f16(
                        af[rf], bf[cf], acc[rf][cf], 0, 0, 0);

            if (c == CHUNKS - 1) {
                if constexpr (RESCUE) {
                    const int colbase = col0 + jt * 128 + wcol;
#pragma unroll
                    for (int cf = 0; cf < 4; ++cf) {
                        const int col = colbase + cf * 16 + l15;
                        const float ch = cHalf[col];
#pragma unroll
                        for (int rf = 0; rf < 4; ++rf)
#pragma unroll
                            for (int r = 0; r < 4; ++r) {
                                float s = acc[rf][cf][r] - ch;
                                int slot = rf * 4 + r;
                                if (s > bvf[slot]) { bvf[slot] = s; bjf[slot] = col; }
                            }
                    }
                } else {
                    const unsigned colloc = (unsigned)(jt * 128 + wcol);
#pragma unroll
                    for (int cf = 0; cf < 4; ++cf) {
                        const unsigned colb = colloc + cf * 16 + l15;
#pragma unroll
                        for (int rf = 0; rf < 4; ++rf)
#pragma unroll
                            for (int r = 0; r < 4; ++r) {
                                unsigned key = (__float_as_uint(acc[rf][cf][r]) & 0xFFFFF800u) | colb;
                                int slot = rf * 4 + r;
                                unsigned t = umax_(key, k1[slot]);
                                k1[slot] = umin_(k1[slot], key);
                                k2[slot] = umin_(k2[slot], t);
                            }
                    }
                }
#pragma unroll
                for (int rf = 0; rf < 4; ++rf)
#pragma unroll
                    for (int cf = 0; cf < 4; ++cf) acc[rf][cf] = fzero;
            }
        }
    }
#undef LOAD4T

#pragma unroll
    for (int st = 1; st < 16; st <<= 1) {
#pragma unroll
        for (int s = 0; s < 16; ++s) {
            if constexpr (RESCUE) {
                float v2 = __shfl_xor(bvf[s], st, 64);
                int   j2 = __shfl_xor(bjf[s], st, 64);
                if (v2 > bvf[s] || (v2 == bvf[s] && j2 < bjf[s])) { bvf[s] = v2; bjf[s] = j2; }
            } else {
                unsigned o1 = (unsigned)__shfl_xor((int)k1[s], st, 64);
                unsigned o2 = (unsigned)__shfl_xor((int)k2[s], st, 64);
                unsigned t = umax_(k1[s], o1);
                k1[s] = umin_(k1[s], o1);
                k2[s] = umin_(umin_(k2[s], o2), t);
            }
        }
    }

    __syncthreads();
    if constexpr (RESCUE) {
        float* mv = (float*)&As[0][0];
        int*   mj = (int*)&Bs[0][0];
        if (l15 == 0) {
#pragma unroll
            for (int rf = 0; rf < 4; ++rf)
#pragma unroll
                for (int r = 0; r < 4; ++r) {
                    int rloc = wrow + rf * 16 + lq * 4 + r;
                    int slot = rf * 4 + r;
                    mv[rloc * 2 + (wave & 1)] = bvf[slot];
                    mj[rloc * 2 + (wave & 1)] = bjf[slot];
                }
        }
        __syncthreads();
        if (tid < 128) {
            float v0 = mv[tid * 2], v1 = mv[tid * 2 + 1];
            int   j0 = mj[tid * 2], j1 = mj[tid * 2 + 1];
            bool take1 = (v1 > v0) || (v1 == v0 && j1 < j0);
            pv[(size_t)js * CAP + row0 + tid] = take1 ? v1 : v0;
            pj[(size_t)js * CAP + row0 + tid] = take1 ? j1 : j0;
        }
    } else {
        unsigned* mk1 = (unsigned*)&As[0][0];
        unsigned* mk2 = (unsigned*)&Bs[0][0];
        if (l15 == 0) {
#pragma unroll
            for (int rf = 0; rf < 4; ++rf)
#pragma unroll
                for (int r = 0; r < 4; ++r) {
                    int rloc = wrow + rf * 16 + lq * 4 + r;
                    int slot = rf * 4 + r;
                    mk1[rloc * 2 + (wave & 1)] = k1[slot];
                    mk2[rloc * 2 + (wave & 1)] = k2[slot];
                }
        }
        __syncthreads();
        if (tid < 128) {
            unsigned a1 = mk1[tid * 2], b1 = mk1[tid * 2 + 1];
            unsigned a2 = mk2[tid * 2], b2 = mk2[tid * 2 + 1];
            unsigned m1 = umin_(a1, b1);
            unsigned m2 = umin_(umin_(a2, b2), umax_(a1, b1));
            pv[(size_t)js * NROW + row0 + tid] = __uint_as_float(m1 & 0xFFFFF800u);
            pj[(size_t)js * NROW + row0 + tid] = (int)(m1 & 2047u) + js * (JT * 128);
            psv[(size_t)js * NROW + row0 + tid] = __uint_as_float(m2 & 0xFFFFF800u);
        }
    }
}

// ======================= cheap reduce: merge splits, flag, gather =======================

__global__ void vq_reduce_k(const float* __restrict__ pv, const int* __restrict__ pj,
                            const float* __restrict__ psv,
                            const float* __restrict__ norms, const unsigned short* __restrict__ Bh,
                            float* __restrict__ qout, float* __restrict__ iout,
                            float* __restrict__ lout, int* __restrict__ list,
                            int* __restrict__ cnt)
{
    __shared__ int jbuf[64];
    const int row0 = blockIdx.x * 64;
    const int tid = threadIdx.x;
    if (tid < 64) {
        int row = row0 + tid;
        float bv = pv[row]; int bj = pj[row]; float sv = psv[row];
#pragma unroll
        for (int s = 1; s < 4; ++s) {
            float v = pv[(size_t)s * NROW + row];
            int   j = pj[(size_t)s * NROW + row];
            float s2 = psv[(size_t)s * NROW + row];
            bool better = (v > bv) || (v == bv && j < bj);
            float loseBest = better ? bv : v;
            sv = fmaxf(fmaxf(sv, s2), loseBest);
            if (better) { bv = v; bj = j; }
        }
        bool flagged = (bv - sv) < MARGINF;
        if (flagged) {
            int idx = atomicAdd(cnt, 1);
            if (idx < CAP) {
                list[idx] = row;
                jbuf[tid] = -1;
            } else {
                flagged = false;
            }
        }
        float rl = 0.f;
        if (!flagged) {
            iout[row] = (float)bj;
            jbuf[tid] = bj;
            rl = norms[row] - 2.0f * (bv + BIAS - 0.0625f);
        }
#pragma unroll
        for (int off = 32; off; off >>= 1) rl += __shfl_down(rl, off, 64);
        if (tid == 0) atomicAdd(lout, rl * LOSS_SCALE);
    }
    __syncthreads();
    const int lane = tid & 63;
    for (int r = tid >> 6; r < 64; r += 4) {
        int j = jbuf[r];
        if (j >= 0) {
            const _Float16* bp = (const _Float16*)Bh + (size_t)j * BST + lane * 4;
            half4 h = *(const half4*)bp;
            half4 l = *(const half4*)(bp + 288);
            float4 v;
            v.x = (float)h[0] + (float)l[0];
            v.y = (float)h[1] + (float)l[1];
            v.z = (float)h[2] + (float)l[2];
            v.w = (float)h[3] + (float)l[3];
            *(float4*)&qout[(size_t)(row0 + r) * DIM + lane * 4] = v;
        }
    }
}

// ======================= rescue reduce: merge 32 splits, finalize =======================

__global__ void vq_reduce2_k(const float* __restrict__ pv2, const int* __restrict__ pj2,
                             const int* __restrict__ list, const int* __restrict__ cnt,
                             const float* __restrict__ norms, const unsigned short* __restrict__ Bh,
                             float* __restrict__ qout, float* __restrict__ iout,
                             float* __restrict__ lout)
{
    __shared__ int rbuf[64], jb2[64];
    const int n = *cnt < CAP ? *cnt : CAP;
    const int i0 = blockIdx.x * 64;
    if (i0 >= n) return;
    const int tid = threadIdx.x;
    if (tid < 64) {
        int i = i0 + tid;
        float rl = 0.f;
        if (i < n) {
            float bv = pv2[i]; int bj = pj2[i];
#pragma unroll 4
            for (int s = 1; s < 32; ++s) {
                float v = pv2[(size_t)s * CAP + i];
                int   j = pj2[(size_t)s * CAP + i];
                if (v > bv || (v == bv && j < bj)) { bv = v; bj = j; }
            }
            int row = list[i];
            iout[row] = (float)bj;
            rbuf[tid] = row;
            jb2[tid]  = bj;
            rl = norms[row] - 2.0f * bv;
        } else {
            rbuf[tid] = -1;
        }
#pragma unroll
        for (int off = 32; off; off >>= 1) rl += __shfl_down(rl, off, 64);
        if (tid == 0) atomicAdd(lout, rl * LOSS_SCALE);
    }
    __syncthreads();
    const int lane = tid & 63;
    for (int r = tid >> 6; r < 64; r += 4) {
        int row = rbuf[r];
        if (row >= 0) {
            const _Float16* bp = (const _Float16*)Bh + (size_t)jb2[r] * BST + lane * 4;
            half4 h = *(const half4*)bp;
            half4 l = *(const half4*)(bp + 288);
            float4 v;
            v.x = (float)h[0] + (float)l[0];
            v.y = (float)h[1] + (float)l[1];
            v.z = (float)h[2] + (float)l[2];
            v.w = (float)h[3] + (float)l[3];
            *(float4*)&qout[(size_t)row * DIM + lane * 4] = v;
        }
    }
}

// ======================= fallback fp32 path (round-1, known-good) =======================

__global__ void transpose_k(const float* __restrict__ e, float* __restrict__ eT) {
    __shared__ float t[32][33];
    int jb = blockIdx.x * 32, db = blockIdx.y * 32;
#pragma unroll
    for (int i = 0; i < 4; ++i)
        t[threadIdx.y + i * 8][threadIdx.x] =
            e[(size_t)(db + threadIdx.y + i * 8) * NC + jb + threadIdx.x];
    __syncthreads();
#pragma unroll
    for (int i = 0; i < 4; ++i)
        eT[(size_t)(jb + threadIdx.y + i * 8) * DIM + db + threadIdx.x] =
            t[threadIdx.x][threadIdx.y + i * 8];
}

__global__ void row_norms_k(const float* __restrict__ x, float* __restrict__ norms) {
    int row  = blockIdx.x * 4 + (threadIdx.x >> 6);
    int lane = threadIdx.x & 63;
    const float4 v = ((const float4*)(x + (size_t)row * DIM))[lane];
    float s = v.x * v.x + v.y * v.y + v.z * v.z + v.w * v.w;
#pragma unroll
    for (int off = 32; off; off >>= 1) s += __shfl_down(s, off, 64);
    if (lane == 0) norms[row] = s;
}

__global__ void code_norms_fb_k(const float* __restrict__ e, float* __restrict__ cHalf) {
    int j = blockIdx.x * 256 + threadIdx.x;
    float s = 0.f;
    for (int d = 0; d < DIM; ++d) { float v = e[(size_t)d * NC + j]; s += v * v; }
    cHalf[j] = 0.5f * s;
}

__global__ __launch_bounds__(256, 4) void vq_main_k(
    const float* __restrict__ x, const float* __restrict__ e,
    const float* __restrict__ eT, const float* __restrict__ norms,
    const float* __restrict__ cHalf, float* __restrict__ qout,
    float* __restrict__ iout, float* __restrict__ lout, int useT)
{
    __shared__ float  As[2][32 * 68];
    __shared__ float4 Bs[2][512];
    const int tid  = threadIdx.x;
    const int row0 = blockIdx.x * 64;
    const int ty = tid >> 4, tx = tid & 15;
    const int ar = tid >> 2, ak = (tid & 3) * 4;
    const int bk = tid >> 4, bj = tid & 15;
    float bestv[4]; int bestj[4];
#pragma unroll
    for (int i = 0; i < 4; ++i) { bestv[i] = -3.4e38f; bestj[i] = 0; }
    float acc[4][4];
    float4 pa0, pa1, pb0, pb1;
    {
        const float* xp = x + (size_t)(row0 + ar) * DIM + ak;
        pa0 = *(const float4*)xp;
        pa1 = *(const float4*)(xp + 16);
        const float* ep = e + (size_t)bk * NC + bj * 4;
        pb0 = *(const float4*)ep;
        pb1 = *(const float4*)(ep + 16 * NC);
    }
    int buf = 0;
    for (int c = 0; c < 1024; ++c) {
        const int kc = c & 7;
#pragma unroll
        for (int q = 0; q < 4; ++q) As[buf][(ak + q) * 68 + ar]      = ((const float*)&pa0)[q];
#pragma unroll
        for (int q = 0; q < 4; ++q) As[buf][(16 + ak + q) * 68 + ar] = ((const float*)&pa1)[q];
        Bs[buf][bk * 16 + bj]        = pb0;
        Bs[buf][(bk + 16) * 16 + bj] = pb1;
        __syncthreads();
        if (c + 1 < 1024) {
            int j0n  = ((c + 1) >> 3) * 64;
            int kk0n = ((c + 1) & 7) * 32;
            const float* xp = x + (size_t)(row0 + ar) * DIM + kk0n + ak;
            pa0 = *(const float4*)xp;
            pa1 = *(const float4*)(xp + 16);
            const float* ep = e + (size_t)(kk0n + bk) * NC + j0n + bj * 4;
            pb0 = *(const float4*)ep;
            pb1 = *(const float4*)(ep + 16 * NC);
        }
        if (kc == 0) {
#pragma unroll
            for (int i = 0; i < 4; ++i)
#pragma unroll
                for (int j = 0; j < 4; ++j) acc[i][j] = 0.f;
        }
#pragma unroll
        for (int k = 0; k < 32; ++k) {
            float4 a = *(const float4*)&As[buf][k * 68 + ty * 4];
            float4 b = *(const float4*)&Bs[buf][k * 16 + tx];
            acc[0][0] += a.x * b.x; acc[0][1] += a.x * b.y; acc[0][2] += a.x * b.z; acc[0][3] += a.x * b.w;
            acc[1][0] += a.y * b.x; acc[1][1] += a.y * b.y; acc[1][2] += a.y * b.z; acc[1][3] += a.y * b.w;
            acc[2][0] += a.z * b.x; acc[2][1] += a.z * b.y; acc[2][2] += a.z * b.z; acc[2][3] += a.z * b.w;
            acc[3][0] += a.w * b.x; acc[3][1] += a.w * b.y; acc[3][2] += a.w * b.z; acc[3][3] += a.w * b.w;
        }
        if (kc == 7) {
            int j0 = (c >> 3) * 64;
            float4 ch = *(const float4*)&cHalf[j0 + tx * 4];
            int jb0 = j0 + tx * 4;
#pragma unroll
            for (int i = 0; i < 4; ++i)
#pragma unroll
                for (int j = 0; j < 4; ++j) {
                    float s = acc[i][j] - ((const float*)&ch)[j];
                    if (s > bestv[i]) { bestv[i] = s; bestj[i] = jb0 + j; }
                }
        }
        buf ^= 1;
    }
    __syncthreads();
    float* redv   = &As[0][0];
    int*   redj   = (int*)&As[0][1024];
    int*   idxbuf = (int*)&As[1][0];
#pragma unroll
    for (int i = 0; i < 4; ++i) {
        int r = ty * 4 + i;
        redv[r * 16 + tx] = bestv[i];
        redj[r * 16 + tx] = bestj[i];
    }
    __syncthreads();
    if (tid < 64) {
        float bvv = redv[tid * 16];
        int   bj2 = redj[tid * 16];
#pragma unroll
        for (int t = 1; t < 16; ++t) {
            float v = redv[tid * 16 + t];
            int   j = redj[tid * 16 + t];
            if (v > bvv || (v == bvv && j < bj2)) { bvv = v; bj2 = j; }
        }
        iout[row0 + tid] = (float)bj2;
        idxbuf[tid] = bj2;
        float rl = norms[row0 + tid] - 2.0f * bvv;
#pragma unroll
        for (int off = 32; off; off >>= 1) rl += __shfl_down(rl, off, 64);
        if (tid == 0) atomicAdd(lout, rl * LOSS_SCALE);
    }
    __syncthreads();
    {
        const int rr = tid >> 6, lane = tid & 63;
        for (int r = rr; r < 64; r += 4) {
            int j = idxbuf[r];
            float4 v;
            if (useT) {
                v = *(const float4*)&eT[(size_t)j * DIM + lane * 4];
            } else {
                int d = lane * 4;
                v.x = e[(size_t)d * NC + j];
                v.y = e[(size_t)(d + 1) * NC + j];
                v.z = e[(size_t)(d + 2) * NC + j];
                v.w = e[(size_t)(d + 3) * NC + j];
            }
            *(float4*)&qout[(size_t)(row0 + r) * DIM + lane * 4] = v;
        }
    }
}

// ======================= launch =======================

extern "C" void kernel_launch(void* const* d_in, const int* in_sizes, int n_in,
                              void* d_out, int out_size, void* d_ws, size_t ws_size,
                              hipStream_t stream) {
    const float* x = (const float*)d_in[0];   // [32768, 256]
    const float* e = (const float*)d_in[1];   // [256, 8192]

    float* qout = (float*)d_out;
    float* iout = qout + (size_t)NROW * DIM;
    float* lout = iout + NROW;

    char* ws = (char*)d_ws;
    const size_t offAh    = 0;                    // 32768*576*2 = 37,748,736
    const size_t offBh    = offAh + 37748736;     //  8192*576*2 =  9,437,184
    const size_t offNorms = offBh + 9437184;      //    131,072
    const size_t offCH    = offNorms + 131072;    //     32,768
    const size_t offPV    = offCH + 32768;        //    524,288
    const size_t offPJ    = offPV + 524288;       //    524,288
    const size_t offPSV   = offPJ + 524288;       //    524,288
    const size_t offPV2   = offPSV + 524288;      //  2,097,152
    const size_t offPJ2   = offPV2 + 2097152;     //  2,097,152
    const size_t offList  = offPJ2 + 2097152;     //     65,536
    const size_t offCnt   = offList + 65536;      //        256
    const size_t needFast = offCnt + 256;         // ~53.2 MB (proven: >=55.7 MB available)

    hipMemsetAsync(lout, 0, sizeof(float), stream);

    if (ws_size >= needFast) {
        unsigned short* Ah = (unsigned short*)(ws + offAh);
        unsigned short* Bh = (unsigned short*)(ws + offBh);
        float* norms = (float*)(ws + offNorms);
        float* cHalf = (float*)(ws + offCH);
        float* pv    = (float*)(ws + offPV);
        int*   pj    = (int*)(ws + offPJ);
        float* psv   = (float*)(ws + offPSV);
        float* pv2   = (float*)(ws + offPV2);
        int*   pj2   = (int*)(ws + offPJ2);
        int*   list  = (int*)(ws + offList);
        int*   cnt   = (int*)(ws + offCnt);

        hipMemsetAsync(cnt, 0, sizeof(int), stream);
        prep_a_k<<<NROW / 4, 256, 0, stream>>>(x, Ah, norms);
        code_norms_k<<<NC / 256, 256, 0, stream>>>(e, Bh, cHalf);
        prep_b_k<<<dim3(NC / 32, DIM / 32), dim3(32, 8), 0, stream>>>(e, Bh);
        // cheap pass (R21): B direct-from-global into registers; LDS = A + chl only;
        // zero-barrier, zero-LDS-write main loop
        vq_cheap_k<<<1024, 512, 0, stream>>>(Ah, Bh, cHalf, pv, pj, psv);
        // merge + flag + finalize non-flagged
        vq_reduce_k<<<NROW / 64, 256, 0, stream>>>(
            pv, pj, psv, norms, Bh, qout, iout, lout, list, cnt);
        // precise pass (R19: 3-deep ring + counted vmcnt) on flagged rows
        vq_gemm_k<24, 2, 5, true><<<(CAP / 128) * 32, 256, 0, stream>>>(
            Ah, Bh, cHalf, pv2, pj2, nullptr, list, cnt);
        vq_reduce2_k<<<CAP / 64, 256, 0, stream>>>(
            pv2, pj2, list, cnt, norms, Bh, qout, iout, lout);
    } else {
        // round-1 fp32 fallback
        float* fws   = (float*)d_ws;
        float* norms = fws;
        float* cHalf = fws + NROW;
        float* eT    = fws + NROW + NC;
        size_t need_T = (size_t)(NROW + NC) * sizeof(float) + (size_t)NC * DIM * sizeof(float);
        int useT = (ws_size >= need_T) ? 1 : 0;
        row_norms_k<<<NROW / 4, 256, 0, stream>>>(x, norms);
        code_norms_fb_k<<<NC / 256, 256, 0, stream>>>(e, cHalf);
        if (useT)
            transpose_k<<<dim3(NC / 32, DIM / 32), dim3(32, 8), 0, stream>>>(e, eT);
        vq_main_k<<<NROW / 64, 256, 0, stream>>>(x, e, eT, norms, cHalf, qout, iout, lout, useT);
    }
}

// Round 17
// 343.661 us; speedup vs baseline: 1.2740x; 1.2740x over previous
//
#include <hip/hip_runtime.h>
#include <hip/hip_fp16.h>

#define NROW 32768
#define DIM  256
#define NC   8192
#define CAP  16384                     // max rescued rows (expect ~2500)
#define MARGINF 0.25f                  // flag threshold: not-flagged => true cheap gap >= 0.125
#define BIAS 512.0f                    // cheap-score bias: guarantees all cheap scores negative
#define AST 576                        // A' row: [hi 256 | ones 32 | lo 256 | pad 32] halves
#define BST 576                        // B' row: [hi 256 | ch 32   | lo 256 | pad 32] halves
#define LOSS_SCALE (1.0f / 8388608.0f)

typedef __attribute__((ext_vector_type(8))) _Float16 half8;
typedef __attribute__((ext_vector_type(4))) _Float16 half4;
typedef __attribute__((ext_vector_type(4))) float   floatx4;
typedef const __attribute__((address_space(1))) void* gas_p;
typedef __attribute__((address_space(3))) void*       las_p;

static __device__ __forceinline__ unsigned short f2hb(float f) {
    _Float16 h = (_Float16)f;
    unsigned short u;
    __builtin_memcpy(&u, &h, 2);
    return u;
}
static __device__ __forceinline__ unsigned umin_(unsigned a, unsigned b) { return a < b ? a : b; }
static __device__ __forceinline__ unsigned umax_(unsigned a, unsigned b) { return a > b ? a : b; }

// ======================= prep kernels (fast path) =======================

__global__ void prep_a_k(const float* __restrict__ x, unsigned short* __restrict__ Ah,
                         float* __restrict__ norms) {
    int row  = blockIdx.x * 4 + (threadIdx.x >> 6);
    int lane = threadIdx.x & 63;
    const float4 v = ((const float4*)(x + (size_t)row * DIM))[lane];
    float s = v.x * v.x + v.y * v.y + v.z * v.z + v.w * v.w;
#pragma unroll
    for (int off = 32; off; off >>= 1) s += __shfl_down(s, off, 64);
    if (lane == 0) norms[row] = s;
    ushort4 hi4 = make_ushort4(f2hb(v.x), f2hb(v.y), f2hb(v.z), f2hb(v.w));
    ushort4 lo4 = make_ushort4(f2hb(v.x - (float)(_Float16)v.x),
                               f2hb(v.y - (float)(_Float16)v.y),
                               f2hb(v.z - (float)(_Float16)v.z),
                               f2hb(v.w - (float)(_Float16)v.w));
    unsigned short* rp = Ah + (size_t)row * AST;
    *(ushort4*)(rp + lane * 4)       = hi4;
    *(ushort4*)(rp + 288 + lane * 4) = lo4;
    if (lane < 8) {                    // legacy ones block (unused by cheap)
        ushort4 ob = make_ushort4(0, 0, 0, 0);
        if (lane == 0) { ob.x = 0x3C00; ob.y = 0x3C00; }
        *(ushort4*)(rp + 256 + lane * 4) = ob;
    }
}

__global__ void code_norms_k(const float* __restrict__ e, unsigned short* __restrict__ Bh,
                             float* __restrict__ cHalf) {
    int j = blockIdx.x * 256 + threadIdx.x;
    float s = 0.f;
    for (int d = 0; d < DIM; ++d) { float v = e[(size_t)d * NC + j]; s += v * v; }
    cHalf[j] = 0.5f * s;
    float t = -0.5f * s - BIAS;        // legacy ch block (unused by cheap)
    unsigned short hi = f2hb(t);
    _Float16 hf; __builtin_memcpy(&hf, &hi, 2);
    unsigned short lo = f2hb(t - (float)hf);
    unsigned short* p = Bh + (size_t)j * BST + 256;
    p[0] = hi; p[1] = lo;
    for (int k2 = 2; k2 < 32; ++k2) p[k2] = 0;
}

__global__ void prep_b_k(const float* __restrict__ e, unsigned short* __restrict__ Bh) {
    __shared__ float t[32][33];
    int jb = blockIdx.x * 32, db = blockIdx.y * 32;
#pragma unroll
    for (int i = 0; i < 4; ++i)
        t[threadIdx.y + i * 8][threadIdx.x] =
            e[(size_t)(db + threadIdx.y + i * 8) * NC + jb + threadIdx.x];
    __syncthreads();
#pragma unroll
    for (int i = 0; i < 4; ++i) {
        int j = jb + threadIdx.y + i * 8;
        int d = db + threadIdx.x;
        float val = t[threadIdx.x][threadIdx.y + i * 8];
        Bh[(size_t)j * BST + d]       = f2hb(val);
        Bh[(size_t)j * BST + 288 + d] = f2hb(val - (float)(_Float16)val);
    }
}

// ======================= R15 cheap kernel (best: 174 us) — final =======================
// Final configuration. Mechanisms that compound here: counted vmcnt(2), counted
// lgkmcnt(4) across the barrier, half-A register residency (ar[4][4]), MFMA-first
// bodies. Every structural neighbor tested (stagger x2, barrier-free x2, 2 blocks/CU,
// B-direct-from-global, full-A residency) regressed or spilled; this is the plateau for
// the 128x2048 / 8-wave / 64x64-tile shape at 2 waves/SIMD.

#define WAITBAR asm volatile("s_waitcnt vmcnt(2) lgkmcnt(4)\n\ts_barrier" ::: "memory")

__global__ __launch_bounds__(512, 2) void vq_cheap_k(
    const unsigned short* __restrict__ Ah, const unsigned short* __restrict__ Bh,
    const float* __restrict__ cHalf,
    float* __restrict__ pv, int* __restrict__ pj, float* __restrict__ psv)
{
    __shared__ __align__(16) _Float16 Asl[8][4096];   // 64 KB: A staging (chunks 4-7 read all loop)
    __shared__ __align__(16) _Float16 Bsl[4][8192];   // 64 KB: 4-deep chunk ring
    __shared__ float chl[2048];                       //  8 KB

    const int tid  = threadIdx.x;
    const int js   = blockIdx.x & 3;
    const int rb   = blockIdx.x >> 2;
    const int row0 = rb * 128, col0 = js * 2048;
    const int lane = tid & 63, l15 = lane & 15, lq = lane >> 4;
    const int wave = tid >> 6;                 // 0..7
    const int wr = (wave >> 2) * 64;           // 0 / 64
    const int wc = (wave & 3) * 64;            // 0 / 64 / 128 / 192
    const int sr = tid >> 2;                   // staging row 0..127
    const int ks = (((tid & 3) ^ (sr & 3) ^ ((sr >> 2) & 3))) * 8;  // swizzled global k-offset

    // ---- chl first: its compiler-inserted vmcnt wait covers only 1 load ----
    {
        float4 a = ((const float4*)(cHalf + col0))[tid];
        a.x += BIAS; a.y += BIAS; a.z += BIAS; a.w += BIAS;
        ((float4*)chl)[tid] = a;
    }

    // ---- A-hi -> LDS (one inst per chunk) ----
    const unsigned short* Abase = Ah + (size_t)(row0 + sr) * AST + ks;
#pragma unroll
    for (int c = 0; c < 8; ++c)
        __builtin_amdgcn_global_load_lds((gas_p)(Abase + c * 32), (las_p)&Asl[c][tid * 8], 16, 0, 0);

#define LOADB(JT_, C_, BUF_)                                                                  \
    do {                                                                                      \
        const unsigned short* bb_ = Bh + (size_t)(col0 + (JT_) * 256 + sr) * BST + (C_) * 32 + ks; \
        _Float16* lb_ = &Bsl[(BUF_)][tid * 8];                                                \
        __builtin_amdgcn_global_load_lds((gas_p)bb_,               (las_p)lb_,          16, 0, 0); \
        __builtin_amdgcn_global_load_lds((gas_p)(bb_ + 128 * BST), (las_p)(lb_ + 4096), 16, 0, 0); \
    } while (0)

    // ---- prime the ring: chunks 0,1,2 in flight ----
    LOADB(0, 0, 0);
    LOADB(0, 1, 1);
    LOADB(0, 2, 2);

    unsigned k1[16], k2[16];
#pragma unroll
    for (int s = 0; s < 16; ++s) { k1[s] = 0xFFFFFFFFu; k2[s] = 0xFFFFFFFFu; }

    const floatx4 fzero = {0.0f, 0.0f, 0.0f, 0.0f};
    floatx4 acc[4][4];
#pragma unroll
    for (int rf = 0; rf < 4; ++rf)
#pragma unroll
        for (int cf = 0; cf < 4; ++cf) acc[rf][cf] = fzero;

    // outstanding: 8 A + 6 B (chl already retired). vmcnt(2) -> A all staged,
    // B chunks 0,1 staged, chunk 2 in flight.
    WAITBAR;

    // ---- one-time: A chunks 0-3 -> registers (64 VGPR) ----
    half8 ar[4][4];
#pragma unroll
    for (int c = 0; c < 4; ++c)
#pragma unroll
        for (int rf = 0; rf < 4; ++rf) {
            const int m = wr + rf * 16 + l15;
            const int g = lq ^ (m & 3) ^ ((m >> 2) & 3);
            ar[c][rf] = *(const half8*)&Asl[c][m * 32 + g * 8];
        }

    // ---- prime bf with chunk 0; af first used body 4, first written at end of body 3 ----
    half8 af[4], bf[4];
#pragma unroll
    for (int cf = 0; cf < 4; ++cf) {
        const int n = wc + cf * 16 + l15;
        const int g = lq ^ (n & 3) ^ ((n >> 2) & 3);
        bf[cf] = *(const half8*)&Bsl[0][n * 32 + g * 8];
    }

    for (int jt = 0; jt < 8; ++jt) {
#pragma unroll
        for (int c = 0; c < 8; ++c) {
            // prefetch chunk t+3 into buf (t+3)&3 (slot's reads were consumed by
            // body t-1's MFMA -> drained at least one barrier before this write)
            if (c <= 4) LOADB(jt, c + 3, (c + 3) & 3);
            else        LOADB((jt + 1) & 7, c - 5, (c + 3) & 3);

            // MFMA chunk t FIRST: A from ar (c<4) or af (read end of body t-1);
            // B from bf (read end of body t-1). Compiler inserts the precise
            // lgkmcnt before each consuming MFMA (bf reads may cross the barrier).
            __builtin_amdgcn_s_setprio(1);
            if (c < 4) {
#pragma unroll
                for (int rf = 0; rf < 4; ++rf)
#pragma unroll
                    for (int cf = 0; cf < 4; ++cf)
                        acc[rf][cf] = __builtin_amdgcn_mfma_f32_16x16x32_f16(
                            ar[c][rf], bf[cf], acc[rf][cf], 0, 0, 0);
            } else {
#pragma unroll
                for (int rf = 0; rf < 4; ++rf)
#pragma unroll
                    for (int cf = 0; cf < 4; ++cf)
                        acc[rf][cf] = __builtin_amdgcn_mfma_f32_16x16x32_f16(
                            af[rf], bf[cf], acc[rf][cf], 0, 0, 0);
            }
            __builtin_amdgcn_s_setprio(0);
            __builtin_amdgcn_sched_barrier(0);  // keep everything below the MFMAs

            if (c == 7) {
                // ---- per-jt epilogue BEFORE the reads: chl reads are consumed
                // in-place; issuing them after bf would force an in-order drain
                // of bf at the barrier. ----
#pragma unroll
                for (int cf = 0; cf < 4; ++cf) {
                    const unsigned colb = (unsigned)(jt * 256 + wc + cf * 16 + l15); // 11-bit local col
                    const float ch = chl[colb];
#pragma unroll
                    for (int rf = 0; rf < 4; ++rf)
#pragma unroll
                        for (int r = 0; r < 4; ++r) {
                            float s = acc[rf][cf][r] - ch;
                            unsigned key = (__float_as_uint(s) & 0xFFFFF800u) | colb;
                            int slot = rf * 4 + r;
                            unsigned t = umax_(key, k1[slot]);
                            k1[slot] = umin_(k1[slot], key);
                            k2[slot] = umin_(k2[slot], t);
                        }
                }
#pragma unroll
                for (int rf = 0; rf < 4; ++rf)
#pragma unroll
                    for (int cf = 0; cf < 4; ++cf) acc[rf][cf] = fzero;
            }

            // ds_reads for chunk t+1 (staged + published by WAITBAR(t-1)); these
            // may remain in flight across the barrier (lgkmcnt(4)).
            if (((c + 1) & 7) >= 4) {
#pragma unroll
                for (int rf = 0; rf < 4; ++rf) {
                    const int m = wr + rf * 16 + l15;
                    const int g = lq ^ (m & 3) ^ ((m >> 2) & 3);
                    af[rf] = *(const half8*)&Asl[(c + 1) & 7][m * 32 + g * 8];
                }
            }
#pragma unroll
            for (int cf = 0; cf < 4; ++cf) {
                const int n = wc + cf * 16 + l15;
                const int g = lq ^ (n & 3) ^ ((n >> 2) & 3);
                bf[cf] = *(const half8*)&Bsl[(c + 1) & 3][n * 32 + g * 8];
            }

            // end of body t: retire chunk t+2 (t+3 in flight); allow this body's
            // newest <=4 LDS reads to cross the barrier.
            WAITBAR;
        }
    }
#undef LOADB

    // ---- cross-lane merge over the 16 l15-lanes of each row-group ----
#pragma unroll
    for (int st = 1; st < 16; st <<= 1) {
#pragma unroll
        for (int s = 0; s < 16; ++s) {
            unsigned o1 = (unsigned)__shfl_xor((int)k1[s], st, 64);
            unsigned o2 = (unsigned)__shfl_xor((int)k2[s], st, 64);
            unsigned t = umax_(k1[s], o1);
            k1[s] = umin_(k1[s], o1);
            k2[s] = umin_(umin_(k2[s], o2), t);
        }
    }

    // ---- merge the four column-group waves per row through LDS ----
    __syncthreads();                            // full drain: dummy tail loads + stray reads
    unsigned* mk1 = (unsigned*)&Asl[0][0];      // [128 rows][4 col-groups]
    unsigned* mk2 = (unsigned*)&Asl[1][0];
    if (l15 == 0) {
#pragma unroll
        for (int rf = 0; rf < 4; ++rf)
#pragma unroll
            for (int r = 0; r < 4; ++r) {
                int rloc = wr + rf * 16 + lq * 4 + r;
                int slot = rf * 4 + r;
                mk1[rloc * 4 + (wave & 3)] = k1[slot];
                mk2[rloc * 4 + (wave & 3)] = k2[slot];
            }
    }
    __syncthreads();
    if (tid < 128) {
        unsigned a0 = mk1[tid * 4], a1 = mk1[tid * 4 + 1], a2 = mk1[tid * 4 + 2], a3 = mk1[tid * 4 + 3];
        unsigned x = umin_(a0, a1), y = umax_(a0, a1);
        unsigned z = umin_(a2, a3), w = umax_(a2, a3);
        unsigned m1  = umin_(x, z);
        unsigned sm1 = umin_(umax_(x, z), umin_(y, w));            // 2nd-best of the four bests
        unsigned s0 = mk2[tid * 4], s1 = mk2[tid * 4 + 1], s2 = mk2[tid * 4 + 2], s3 = mk2[tid * 4 + 3];
        unsigned m2 = umin_(umin_(umin_(s0, s1), umin_(s2, s3)), sm1);
        pv[(size_t)js * NROW + row0 + tid]  = __uint_as_float(m1 & 0xFFFFF800u);
        pj[(size_t)js * NROW + row0 + tid]  = (int)(m1 & 2047u) + js * 2048;
        psv[(size_t)js * NROW + row0 + tid] = __uint_as_float(m2 & 0xFFFFF800u);
    }
}

#undef WAITBAR

// ======================= rescue GEMM: R19 — 3-deep ring + counted vmcnt =======================

template<bool RESCUE>
static __device__ __forceinline__ void chunk_off(int c, int& ac, int& bc) {
    if constexpr (RESCUE) {
        if (c < 8)       { ac = c * 32;              bc = c * 32; }
        else if (c < 16) { ac = (c - 8) * 32;        bc = 288 + (c - 8) * 32; }
        else             { ac = 288 + (c - 16) * 32; bc = (c - 16) * 32; }
    } else {
        ac = c * 32; bc = c * 32;
    }
}

#define GWAIT asm volatile("s_waitcnt vmcnt(4) lgkmcnt(0)\n\ts_barrier" ::: "memory")

template<int CHUNKS, int JT, int JSB, bool RESCUE>
__global__ __launch_bounds__(256, 2) void vq_gemm_k(
    const unsigned short* __restrict__ Ah, const unsigned short* __restrict__ Bh,
    const float* __restrict__ cHalf,
    float* __restrict__ pv, int* __restrict__ pj, float* __restrict__ psv,
    const int* __restrict__ list, const int* __restrict__ cnt)
{
    static_assert(CHUNKS % 3 == 0, "3-deep ring requires CHUNKS % 3 == 0");
    __shared__ __align__(16) _Float16 As[3][4096];    // 24 KB
    __shared__ __align__(16) _Float16 Bs[3][4096];    // 24 KB

    const int tid  = threadIdx.x;
    const int js   = blockIdx.x & ((1 << JSB) - 1);
    const int rb   = blockIdx.x >> JSB;
    const int row0 = rb * 128, col0 = js * (JT * 128);
    const int lane = tid & 63, l15 = lane & 15, lq = lane >> 4;
    const int wave = tid >> 6;
    const int wrow = (wave >> 1) * 64, wcol = (wave & 1) * 64;
    const int sr = tid >> 2, sp = (tid & 3) * 8;

    int nact = 0;
    if constexpr (RESCUE) {
        nact = *cnt;
        if (row0 >= nact) return;
    }

    const unsigned short *Abase0, *Abase1;
    if constexpr (RESCUE) {
        int i0 = row0 + sr, i1 = i0 + 64;
        int r0 = (i0 < nact) ? list[i0] : 0;
        int r1 = (i1 < nact) ? list[i1] : 0;
        Abase0 = Ah + (size_t)r0 * AST + sp;
        Abase1 = Ah + (size_t)r1 * AST + sp;
    } else {
        Abase0 = Ah + (size_t)(row0 + sr) * AST + sp;
        Abase1 = Abase0 + 64 * AST;
    }

    unsigned k1[16], k2[16];
    float bvf[16]; int bjf[16];
#pragma unroll
    for (int s = 0; s < 16; ++s) {
        k1[s] = 0xFFFFFFFFu; k2[s] = 0xFFFFFFFFu;
        bvf[s] = -3.4e38f; bjf[s] = 0;
    }

    const floatx4 fzero = {0.0f, 0.0f, 0.0f, 0.0f};
    floatx4 acc[4][4];
#pragma unroll
    for (int rf = 0; rf < 4; ++rf)
#pragma unroll
        for (int cf = 0; cf < 4; ++cf) acc[rf][cf] = fzero;

    const unsigned short* Bb0 = Bh + (size_t)(col0 + sr) * BST + sp;

#define LOAD4T(JT_, C_)                                                                      \
    do {                                                                                     \
        int an_, bn_;                                                                        \
        chunk_off<RESCUE>((C_), an_, bn_);                                                   \
        const unsigned short* bb_ = Bb0 + (size_t)(JT_) * (128 * BST);                       \
        _Float16* la_ = &As[(C_) % 3][tid * 8];                                              \
        _Float16* lb_ = &Bs[(C_) % 3][tid * 8];                                              \
        __builtin_amdgcn_global_load_lds((gas_p)(Abase0 + an_),            (las_p)la_,          16, 0, 0); \
        __builtin_amdgcn_global_load_lds((gas_p)(Abase1 + an_),            (las_p)(la_ + 2048), 16, 0, 0); \
        __builtin_amdgcn_global_load_lds((gas_p)(bb_ + bn_),               (las_p)lb_,          16, 0, 0); \
        __builtin_amdgcn_global_load_lds((gas_p)(bb_ + 64 * BST + bn_),    (las_p)(lb_ + 2048), 16, 0, 0); \
    } while (0)

    LOAD4T(0, 0);
    LOAD4T(0, 1);

    for (int jt = 0; jt < JT; ++jt) {
#pragma unroll
        for (int c = 0; c < CHUNKS; ++c) {
            GWAIT;
            if (c + 2 < CHUNKS)       LOAD4T(jt, c + 2);
            else if (jt + 1 < JT)     LOAD4T(jt + 1, c + 2 - CHUNKS);

            half8 af[4], bf[4];
#pragma unroll
            for (int rf = 0; rf < 4; ++rf)
                af[rf] = *(const half8*)&As[c % 3][(wrow + rf * 16 + l15) * 32 + lq * 8];
#pragma unroll
            for (int cf = 0; cf < 4; ++cf)
                bf[cf] = *(const half8*)&Bs[c % 3][(wcol + cf * 16 + l15) * 32 + lq * 8];
#pragma unroll
            for (int rf = 0; rf < 4; ++rf)
#pragma unroll
                for (int cf = 0; cf < 4; ++cf)
                    acc[rf][cf] = __builtin_amdgcn_mfma_f32_16x16x32_f16(
                        af[rf], bf[cf], acc[rf][cf], 0, 0, 0);

            if (c == CHUNKS - 1) {
                if constexpr (RESCUE) {
                    const int colbase = col0 + jt * 128 + wcol;
#pragma unroll
                    for (int cf = 0; cf < 4; ++cf) {
                        const int col = colbase + cf * 16 + l15;
                        const float ch = cHalf[col];
#pragma unroll
                        for (int rf = 0; rf < 4; ++rf)
#pragma unroll
                            for (int r = 0; r < 4; ++r) {
                                float s = acc[rf][cf][r] - ch;
                                int slot = rf * 4 + r;
                                if (s > bvf[slot]) { bvf[slot] = s; bjf[slot] = col; }
                            }
                    }
                } else {
                    const unsigned colloc = (unsigned)(jt * 128 + wcol);
#pragma unroll
                    for (int cf = 0; cf < 4; ++cf) {
                        const unsigned colb = colloc + cf * 16 + l15;
#pragma unroll
                        for (int rf = 0; rf < 4; ++rf)
#pragma unroll
                            for (int r = 0; r < 4; ++r) {
                                unsigned key = (__float_as_uint(acc[rf][cf][r]) & 0xFFFFF800u) | colb;
                                int slot = rf * 4 + r;
                                unsigned t = umax_(key, k1[slot]);
                                k1[slot] = umin_(k1[slot], key);
                                k2[slot] = umin_(k2[slot], t);
                            }
                    }
                }
#pragma unroll
                for (int rf = 0; rf < 4; ++rf)
#pragma unroll
                    for (int cf = 0; cf < 4; ++cf) acc[rf][cf] = fzero;
            }
        }
    }
#undef LOAD4T

#pragma unroll
    for (int st = 1; st < 16; st <<= 1) {
#pragma unroll
        for (int s = 0; s < 16; ++s) {
            if constexpr (RESCUE) {
                float v2 = __shfl_xor(bvf[s], st, 64);
                int   j2 = __shfl_xor(bjf[s], st, 64);
                if (v2 > bvf[s] || (v2 == bvf[s] && j2 < bjf[s])) { bvf[s] = v2; bjf[s] = j2; }
            } else {
                unsigned o1 = (unsigned)__shfl_xor((int)k1[s], st, 64);
                unsigned o2 = (unsigned)__shfl_xor((int)k2[s], st, 64);
                unsigned t = umax_(k1[s], o1);
                k1[s] = umin_(k1[s], o1);
                k2[s] = umin_(umin_(k2[s], o2), t);
            }
        }
    }

    __syncthreads();
    if constexpr (RESCUE) {
        float* mv = (float*)&As[0][0];
        int*   mj = (int*)&Bs[0][0];
        if (l15 == 0) {
#pragma unroll
            for (int rf = 0; rf < 4; ++rf)
#pragma unroll
                for (int r = 0; r < 4; ++r) {
                    int rloc = wrow + rf * 16 + lq * 4 + r;
                    int slot = rf * 4 + r;
                    mv[rloc * 2 + (wave & 1)] = bvf[slot];
                    mj[rloc * 2 + (wave & 1)] = bjf[slot];
                }
        }
        __syncthreads();
        if (tid < 128) {
            float v0 = mv[tid * 2], v1 = mv[tid * 2 + 1];
            int   j0 = mj[tid * 2], j1 = mj[tid * 2 + 1];
            bool take1 = (v1 > v0) || (v1 == v0 && j1 < j0);
            pv[(size_t)js * CAP + row0 + tid] = take1 ? v1 : v0;
            pj[(size_t)js * CAP + row0 + tid] = take1 ? j1 : j0;
        }
    } else {
        unsigned* mk1 = (unsigned*)&As[0][0];
        unsigned* mk2 = (unsigned*)&Bs[0][0];
        if (l15 == 0) {
#pragma unroll
            for (int rf = 0; rf < 4; ++rf)
#pragma unroll
                for (int r = 0; r < 4; ++r) {
                    int rloc = wrow + rf * 16 + lq * 4 + r;
                    int slot = rf * 4 + r;
                    mk1[rloc * 2 + (wave & 1)] = k1[slot];
                    mk2[rloc * 2 + (wave & 1)] = k2[slot];
                }
        }
        __syncthreads();
        if (tid < 128) {
            unsigned a1 = mk1[tid * 2], b1 = mk1[tid * 2 + 1];
            unsigned a2 = mk2[tid * 2], b2 = mk2[tid * 2 + 1];
            unsigned m1 = umin_(a1, b1);
            unsigned m2 = umin_(umin_(a2, b2), umax_(a1, b1));
            pv[(size_t)js * NROW + row0 + tid] = __uint_as_float(m1 & 0xFFFFF800u);
            pj[(size_t)js * NROW + row0 + tid] = (int)(m1 & 2047u) + js * (JT * 128);
            psv[(size_t)js * NROW + row0 + tid] = __uint_as_float(m2 & 0xFFFFF800u);
        }
    }
}

// ======================= cheap reduce: merge splits, flag, gather =======================

__global__ void vq_reduce_k(const float* __restrict__ pv, const int* __restrict__ pj,
                            const float* __restrict__ psv,
                            const float* __restrict__ norms, const unsigned short* __restrict__ Bh,
                            float* __restrict__ qout, float* __restrict__ iout,
                            float* __restrict__ lout, int* __restrict__ list,
                            int* __restrict__ cnt)
{
    __shared__ int jbuf[64];
    const int row0 = blockIdx.x * 64;
    const int tid = threadIdx.x;
    if (tid < 64) {
        int row = row0 + tid;
        float bv = pv[row]; int bj = pj[row]; float sv = psv[row];
#pragma unroll
        for (int s = 1; s < 4; ++s) {
            float v = pv[(size_t)s * NROW + row];
            int   j = pj[(size_t)s * NROW + row];
            float s2 = psv[(size_t)s * NROW + row];
            bool better = (v > bv) || (v == bv && j < bj);
            float loseBest = better ? bv : v;
            sv = fmaxf(fmaxf(sv, s2), loseBest);
            if (better) { bv = v; bj = j; }
        }
        bool flagged = (bv - sv) < MARGINF;
        if (flagged) {
            int idx = atomicAdd(cnt, 1);
            if (idx < CAP) {
                list[idx] = row;
                jbuf[tid] = -1;
            } else {
                flagged = false;
            }
        }
        float rl = 0.f;
        if (!flagged) {
            iout[row] = (float)bj;
            jbuf[tid] = bj;
            rl = norms[row] - 2.0f * (bv + BIAS - 0.0625f);
        }
#pragma unroll
        for (int off = 32; off; off >>= 1) rl += __shfl_down(rl, off, 64);
        if (tid == 0) atomicAdd(lout, rl * LOSS_SCALE);
    }
    __syncthreads();
    const int lane = tid & 63;
    for (int r = tid >> 6; r < 64; r += 4) {
        int j = jbuf[r];
        if (j >= 0) {
            const _Float16* bp = (const _Float16*)Bh + (size_t)j * BST + lane * 4;
            half4 h = *(const half4*)bp;
            half4 l = *(const half4*)(bp + 288);
            float4 v;
            v.x = (float)h[0] + (float)l[0];
            v.y = (float)h[1] + (float)l[1];
            v.z = (float)h[2] + (float)l[2];
            v.w = (float)h[3] + (float)l[3];
            *(float4*)&qout[(size_t)(row0 + r) * DIM + lane * 4] = v;
        }
    }
}

// ======================= rescue reduce: merge 32 splits, finalize =======================

__global__ void vq_reduce2_k(const float* __restrict__ pv2, const int* __restrict__ pj2,
                             const int* __restrict__ list, const int* __restrict__ cnt,
                             const float* __restrict__ norms, const unsigned short* __restrict__ Bh,
                             float* __restrict__ qout, float* __restrict__ iout,
                             float* __restrict__ lout)
{
    __shared__ int rbuf[64], jb2[64];
    const int n = *cnt < CAP ? *cnt : CAP;
    const int i0 = blockIdx.x * 64;
    if (i0 >= n) return;
    const int tid = threadIdx.x;
    if (tid < 64) {
        int i = i0 + tid;
        float rl = 0.f;
        if (i < n) {
            float bv = pv2[i]; int bj = pj2[i];
#pragma unroll 4
            for (int s = 1; s < 32; ++s) {
                float v = pv2[(size_t)s * CAP + i];
                int   j = pj2[(size_t)s * CAP + i];
                if (v > bv || (v == bv && j < bj)) { bv = v; bj = j; }
            }
            int row = list[i];
            iout[row] = (float)bj;
            rbuf[tid] = row;
            jb2[tid]  = bj;
            rl = norms[row] - 2.0f * bv;
        } else {
            rbuf[tid] = -1;
        }
#pragma unroll
        for (int off = 32; off; off >>= 1) rl += __shfl_down(rl, off, 64);
        if (tid == 0) atomicAdd(lout, rl * LOSS_SCALE);
    }
    __syncthreads();
    const int lane = tid & 63;
    for (int r = tid >> 6; r < 64; r += 4) {
        int row = rbuf[r];
        if (row >= 0) {
            const _Float16* bp = (const _Float16*)Bh + (size_t)jb2[r] * BST + lane * 4;
            half4 h = *(const half4*)bp;
            half4 l = *(const half4*)(bp + 288);
            float4 v;
            v.x = (float)h[0] + (float)l[0];
            v.y = (float)h[1] + (float)l[1];
            v.z = (float)h[2] + (float)l[2];
            v.w = (float)h[3] + (float)l[3];
            *(float4*)&qout[(size_t)row * DIM + lane * 4] = v;
        }
    }
}

// ======================= fallback fp32 path (round-1, known-good) =======================

__global__ void transpose_k(const float* __restrict__ e, float* __restrict__ eT) {
    __shared__ float t[32][33];
    int jb = blockIdx.x * 32, db = blockIdx.y * 32;
#pragma unroll
    for (int i = 0; i < 4; ++i)
        t[threadIdx.y + i * 8][threadIdx.x] =
            e[(size_t)(db + threadIdx.y + i * 8) * NC + jb + threadIdx.x];
    __syncthreads();
#pragma unroll
    for (int i = 0; i < 4; ++i)
        eT[(size_t)(jb + threadIdx.y + i * 8) * DIM + db + threadIdx.x] =
            t[threadIdx.x][threadIdx.y + i * 8];
}

__global__ void row_norms_k(const float* __restrict__ x, float* __restrict__ norms) {
    int row  = blockIdx.x * 4 + (threadIdx.x >> 6);
    int lane = threadIdx.x & 63;
    const float4 v = ((const float4*)(x + (size_t)row * DIM))[lane];
    float s = v.x * v.x + v.y * v.y + v.z * v.z + v.w * v.w;
#pragma unroll
    for (int off = 32; off; off >>= 1) s += __shfl_down(s, off, 64);
    if (lane == 0) norms[row] = s;
}

__global__ void code_norms_fb_k(const float* __restrict__ e, float* __restrict__ cHalf) {
    int j = blockIdx.x * 256 + threadIdx.x;
    float s = 0.f;
    for (int d = 0; d < DIM; ++d) { float v = e[(size_t)d * NC + j]; s += v * v; }
    cHalf[j] = 0.5f * s;
}

__global__ __launch_bounds__(256, 4) void vq_main_k(
    const float* __restrict__ x, const float* __restrict__ e,
    const float* __restrict__ eT, const float* __restrict__ norms,
    const float* __restrict__ cHalf, float* __restrict__ qout,
    float* __restrict__ iout, float* __restrict__ lout, int useT)
{
    __shared__ float  As[2][32 * 68];
    __shared__ float4 Bs[2][512];
    const int tid  = threadIdx.x;
    const int row0 = blockIdx.x * 64;
    const int ty = tid >> 4, tx = tid & 15;
    const int ar = tid >> 2, ak = (tid & 3) * 4;
    const int bk = tid >> 4, bj = tid & 15;
    float bestv[4]; int bestj[4];
#pragma unroll
    for (int i = 0; i < 4; ++i) { bestv[i] = -3.4e38f; bestj[i] = 0; }
    float acc[4][4];
    float4 pa0, pa1, pb0, pb1;
    {
        const float* xp = x + (size_t)(row0 + ar) * DIM + ak;
        pa0 = *(const float4*)xp;
        pa1 = *(const float4*)(xp + 16);
        const float* ep = e + (size_t)bk * NC + bj * 4;
        pb0 = *(const float4*)ep;
        pb1 = *(const float4*)(ep + 16 * NC);
    }
    int buf = 0;
    for (int c = 0; c < 1024; ++c) {
        const int kc = c & 7;
#pragma unroll
        for (int q = 0; q < 4; ++q) As[buf][(ak + q) * 68 + ar]      = ((const float*)&pa0)[q];
#pragma unroll
        for (int q = 0; q < 4; ++q) As[buf][(16 + ak + q) * 68 + ar] = ((const float*)&pa1)[q];
        Bs[buf][bk * 16 + bj]        = pb0;
        Bs[buf][(bk + 16) * 16 + bj] = pb1;
        __syncthreads();
        if (c + 1 < 1024) {
            int j0n  = ((c + 1) >> 3) * 64;
            int kk0n = ((c + 1) & 7) * 32;
            const float* xp = x + (size_t)(row0 + ar) * DIM + kk0n + ak;
            pa0 = *(const float4*)xp;
            pa1 = *(const float4*)(xp + 16);
            const float* ep = e + (size_t)(kk0n + bk) * NC + j0n + bj * 4;
            pb0 = *(const float4*)ep;
            pb1 = *(const float4*)(ep + 16 * NC);
        }
        if (kc == 0) {
#pragma unroll
            for (int i = 0; i < 4; ++i)
#pragma unroll
                for (int j = 0; j < 4; ++j) acc[i][j] = 0.f;
        }
#pragma unroll
        for (int k = 0; k < 32; ++k) {
            float4 a = *(const float4*)&As[buf][k * 68 + ty * 4];
            float4 b = *(const float4*)&Bs[buf][k * 16 + tx];
            acc[0][0] += a.x * b.x; acc[0][1] += a.x * b.y; acc[0][2] += a.x * b.z; acc[0][3] += a.x * b.w;
            acc[1][0] += a.y * b.x; acc[1][1] += a.y * b.y; acc[1][2] += a.y * b.z; acc[1][3] += a.y * b.w;
            acc[2][0] += a.z * b.x; acc[2][1] += a.z * b.y; acc[2][2] += a.z * b.z; acc[2][3] += a.z * b.w;
            acc[3][0] += a.w * b.x; acc[3][1] += a.w * b.y; acc[3][2] += a.w * b.z; acc[3][3] += a.w * b.w;
        }
        if (kc == 7) {
            int j0 = (c >> 3) * 64;
            float4 ch = *(const float4*)&cHalf[j0 + tx * 4];
            int jb0 = j0 + tx * 4;
#pragma unroll
            for (int i = 0; i < 4; ++i)
#pragma unroll
                for (int j = 0; j < 4; ++j) {
                    float s = acc[i][j] - ((const float*)&ch)[j];
                    if (s > bestv[i]) { bestv[i] = s; bestj[i] = jb0 + j; }
                }
        }
        buf ^= 1;
    }
    __syncthreads();
    float* redv   = &As[0][0];
    int*   redj   = (int*)&As[0][1024];
    int*   idxbuf = (int*)&As[1][0];
#pragma unroll
    for (int i = 0; i < 4; ++i) {
        int r = ty * 4 + i;
        redv[r * 16 + tx] = bestv[i];
        redj[r * 16 + tx] = bestj[i];
    }
    __syncthreads();
    if (tid < 64) {
        float bvv = redv[tid * 16];
        int   bj2 = redj[tid * 16];
#pragma unroll
        for (int t = 1; t < 16; ++t) {
            float v = redv[tid * 16 + t];
            int   j = redj[tid * 16 + t];
            if (v > bvv || (v == bvv && j < bj2)) { bvv = v; bj2 = j; }
        }
        iout[row0 + tid] = (float)bj2;
        idxbuf[tid] = bj2;
        float rl = norms[row0 + tid] - 2.0f * bvv;
#pragma unroll
        for (int off = 32; off; off >>= 1) rl += __shfl_down(rl, off, 64);
        if (tid == 0) atomicAdd(lout, rl * LOSS_SCALE);
    }
    __syncthreads();
    {
        const int rr = tid >> 6, lane = tid & 63;
        for (int r = rr; r < 64; r += 4) {
            int j = idxbuf[r];
            float4 v;
            if (useT) {
                v = *(const float4*)&eT[(size_t)j * DIM + lane * 4];
            } else {
                int d = lane * 4;
                v.x = e[(size_t)d * NC + j];
                v.y = e[(size_t)(d + 1) * NC + j];
                v.z = e[(size_t)(d + 2) * NC + j];
                v.w = e[(size_t)(d + 3) * NC + j];
            }
            *(float4*)&qout[(size_t)(row0 + r) * DIM + lane * 4] = v;
        }
    }
}

// ======================= launch =======================

extern "C" void kernel_launch(void* const* d_in, const int* in_sizes, int n_in,
                              void* d_out, int out_size, void* d_ws, size_t ws_size,
                              hipStream_t stream) {
    const float* x = (const float*)d_in[0];   // [32768, 256]
    const float* e = (const float*)d_in[1];   // [256, 8192]

    float* qout = (float*)d_out;
    float* iout = qout + (size_t)NROW * DIM;
    float* lout = iout + NROW;

    char* ws = (char*)d_ws;
    const size_t offAh    = 0;                    // 32768*576*2 = 37,748,736
    const size_t offBh    = offAh + 37748736;     //  8192*576*2 =  9,437,184
    const size_t offNorms = offBh + 9437184;      //    131,072
    const size_t offCH    = offNorms + 131072;    //     32,768
    const size_t offPV    = offCH + 32768;        //    524,288
    const size_t offPJ    = offPV + 524288;       //    524,288
    const size_t offPSV   = offPJ + 524288;       //    524,288
    const size_t offPV2   = offPSV + 524288;      //  2,097,152
    const size_t offPJ2   = offPV2 + 2097152;     //  2,097,152
    const size_t offList  = offPJ2 + 2097152;     //     65,536
    const size_t offCnt   = offList + 65536;      //        256
    const size_t needFast = offCnt + 256;         // ~53.2 MB (proven: >=55.7 MB available)

    hipMemsetAsync(lout, 0, sizeof(float), stream);

    if (ws_size >= needFast) {
        unsigned short* Ah = (unsigned short*)(ws + offAh);
        unsigned short* Bh = (unsigned short*)(ws + offBh);
        float* norms = (float*)(ws + offNorms);
        float* cHalf = (float*)(ws + offCH);
        float* pv    = (float*)(ws + offPV);
        int*   pj    = (int*)(ws + offPJ);
        float* psv   = (float*)(ws + offPSV);
        float* pv2   = (float*)(ws + offPV2);
        int*   pj2   = (int*)(ws + offPJ2);
        int*   list  = (int*)(ws + offList);
        int*   cnt   = (int*)(ws + offCnt);

        hipMemsetAsync(cnt, 0, sizeof(int), stream);
        prep_a_k<<<NROW / 4, 256, 0, stream>>>(x, Ah, norms);
        code_norms_k<<<NC / 256, 256, 0, stream>>>(e, Bh, cHalf);
        prep_b_k<<<dim3(NC / 32, DIM / 32), dim3(32, 8), 0, stream>>>(e, Bh);
        // cheap pass: R15 (best-known)
        vq_cheap_k<<<1024, 512, 0, stream>>>(Ah, Bh, cHalf, pv, pj, psv);
        // merge + flag + finalize non-flagged
        vq_reduce_k<<<NROW / 64, 256, 0, stream>>>(
            pv, pj, psv, norms, Bh, qout, iout, lout, list, cnt);
        // precise pass (R19: 3-deep ring + counted vmcnt) on flagged rows
        vq_gemm_k<24, 2, 5, true><<<(CAP / 128) * 32, 256, 0, stream>>>(
            Ah, Bh, cHalf, pv2, pj2, nullptr, list, cnt);
        vq_reduce2_k<<<CAP / 64, 256, 0, stream>>>(
            pv2, pj2, list, cnt, norms, Bh, qout, iout, lout);
    } else {
        // round-1 fp32 fallback
        float* fws   = (float*)d_ws;
        float* norms = fws;
        float* cHalf = fws + NROW;
        float* eT    = fws + NROW + NC;
        size_t need_T = (size_t)(NROW + NC) * sizeof(float) + (size_t)NC * DIM * sizeof(float);
        int useT = (ws_size >= need_T) ? 1 : 0;
        row_norms_k<<<NROW / 4, 256, 0, stream>>>(x, norms);
        code_norms_fb_k<<<NC / 256, 256, 0, stream>>>(e, cHalf);
        if (useT)
            transpose_k<<<dim3(NC / 32, DIM / 32), dim3(32, 8), 0, stream>>>(e, eT);
        vq_main_k<<<NROW / 64, 256, 0, stream>>>(x, e, eT, norms, cHalf, qout, iout, lout, useT);
    }
}